// Round 3
// baseline (171.910 us; speedup 1.0000x reference)
//
#include <hip/hip_runtime.h>

// LocalCorrRatio on (1,1,90,90,90) fp32. 90%9==0 -> no padding; 1000 patches
// (9x9x9), 32 Parzen bins, 4 correlation-ratio passes:
//   out = -(1/12000) * sum over {conf0..3, patch} of eta^2
// conf pairs (0,1) and (2,3) share voxel data (X/Y roles swapped; shift 0 / 4).
//
// R3: one wave per (shift,patch) computes BOTH directions from one register
// load (2000 blocks). Zero LDS in inner loop; bins rotate across lanes with
// __shfl routing. Second kernel folded in via last-block pattern (counter
// memset node + device-scope atomics). Compute floor ~93M exps ≈ 5-6 us.

constexpr int   NPATCH  = 1000;
constexpr float PRETERM = 961.0f;   // 1/sigma^2, sigma = 1/31

__global__ __launch_bounds__(64)
void cr_patch_kernel(const float* __restrict__ yt,
                     const float* __restrict__ yp,
                     float* __restrict__ partial,      // [2*NPATCH]
                     unsigned* __restrict__ cnt,       // memset to 0 per call
                     float* __restrict__ out)
{
    const int bid     = blockIdx.x;
    const int shifted = (bid >= NPATCH);
    const int p       = shifted ? bid - NPATCH : bid;
    const int shift   = shifted ? 4 : 0;
    const int ph = p / 100, pw = (p / 10) % 10, pd = p % 10;
    const int lane = threadIdx.x;                       // one wave per block

    // ---- Load 729 voxel pairs into registers: lane owns j = lane + 64*v ----
    float xs[12], ys[12];                               // xs = y_true, ys = y_pred
    float st = 0.f, st2 = 0.f, sp = 0.f, sp2 = 0.f;

    auto load_voxel = [&](int j, float& tv, float& pv) {
        int dh  = j / 81;
        int rem = j - dh * 81;
        int dw  = rem / 9;
        int dd  = rem - dw * 9;
        int H = ph * 9 + dh + shift; if (H >= 90) H -= 90;
        int W = pw * 9 + dw + shift; if (W >= 90) W -= 90;
        int D = pd * 9 + dd + shift; if (D >= 90) D -= 90;
        int idx = (H * 90 + W) * 90 + D;
        tv = yt[idx];
        pv = yp[idx];
    };

    #pragma unroll
    for (int v = 0; v < 11; ++v) {
        load_voxel(lane + (v << 6), xs[v], ys[v]);
        st += xs[v]; st2 = fmaf(xs[v], xs[v], st2);
        sp += ys[v]; sp2 = fmaf(ys[v], ys[v], sp2);
    }
    if (lane < 729 - 11 * 64) {                         // lanes 0..24: 12th voxel
        load_voxel(lane + 704, xs[11], ys[11]);
        st += xs[11]; st2 = fmaf(xs[11], xs[11], st2);
        sp += ys[11]; sp2 = fmaf(ys[11], ys[11], sp2);
    } else {
        xs[11] = 10.f; ys[11] = 10.f;                   // exp(-961*(10-c)^2) == 0
    }

    #pragma unroll
    for (int m = 1; m < 64; m <<= 1) {
        st  += __shfl_xor(st,  m);  st2 += __shfl_xor(st2, m);
        sp  += __shfl_xor(sp,  m);  sp2 += __shfl_xor(sp2, m);
    }
    const float meanT = st * (1.0f / 729.0f);
    const float meanP = sp * (1.0f / 729.0f);

    // ---- Parzen accumulation, rotated bin order + shfl routing ----
    const int l5 = lane & 31;
    const int hi = lane & 32;
    float rA_w = 0.f, rA_wx = 0.f;     // dir A: bins on y_pred, intensity y_true
    float rB_w = 0.f, rB_wx = 0.f;     // dir B: bins on y_true, intensity y_pred

    for (int k = 0; k < 32; ++k) {
        const int   b = (l5 + k) & 31;
        const float c = (float)b * (1.0f / 31.0f);
        float aw = 0.f, awx = 0.f, bw = 0.f, bwx = 0.f;
        #pragma unroll
        for (int v = 0; v < 12; ++v) {
            float dA = ys[v] - c;
            float wA = __expf(-PRETERM * dA * dA);
            aw += wA; awx = fmaf(wA, xs[v], awx);
            float dB = xs[v] - c;
            float wB = __expf(-PRETERM * dB * dB);
            bw += wB; bwx = fmaf(wB, ys[v], bwx);
        }
        const int src = hi | ((l5 - k) & 31);
        rA_w  += __shfl(aw,  src, 64);
        rA_wx += __shfl(awx, src, 64);
        rB_w  += __shfl(bw,  src, 64);
        rB_wx += __shfl(bwx, src, 64);
    }
    rA_w += __shfl_xor(rA_w, 32);  rA_wx += __shfl_xor(rA_wx, 32);
    rB_w += __shfl_xor(rB_w, 32);  rB_wx += __shfl_xor(rB_wx, 32);

    // ---- Finalize both eta^2 ----
    float miA = rA_wx / (rA_w + 1e-5f);
    float duA = miA - meanT;
    float tnA = rA_w * duA * duA, tdA = rA_w;
    float miB = rB_wx / (rB_w + 1e-5f);
    float duB = miB - meanP;
    float tnB = rB_w * duB * duB, tdB = rB_w;
    #pragma unroll
    for (int m = 1; m < 32; m <<= 1) {                  // over 32 bins (halves mirror)
        tnA += __shfl_xor(tnA, m);  tdA += __shfl_xor(tdA, m);
        tnB += __shfl_xor(tnB, m);  tdB += __shfl_xor(tdB, m);
    }
    if (lane == 0) {
        float tvT = (st2 - st * st * (1.0f / 729.0f)) * (1.0f / 728.0f);
        float tvP = (sp2 - sp * sp * (1.0f / 729.0f)) * (1.0f / 728.0f);
        float eta = (tnA / tdA) / (tvT + 1e-5f) + (tnB / tdB) / (tvP + 1e-5f);
        __hip_atomic_store(&partial[bid], eta, __ATOMIC_RELAXED, __HIP_MEMORY_SCOPE_AGENT);
    }

    // ---- Last-block final reduction (replaces second kernel) ----
    __threadfence();
    unsigned old = 0;
    if (lane == 0)
        old = __hip_atomic_fetch_add(cnt, 1u, __ATOMIC_ACQ_REL, __HIP_MEMORY_SCOPE_AGENT);
    old = __shfl(old, 0, 64);
    if (old == 2u * NPATCH - 1u) {
        __threadfence();
        float s = 0.f;
        for (int i = lane; i < 2 * NPATCH; i += 64)
            s += __hip_atomic_load(&partial[i], __ATOMIC_RELAXED, __HIP_MEMORY_SCOPE_AGENT);
        #pragma unroll
        for (int m = 1; m < 64; m <<= 1) s += __shfl_xor(s, m);
        if (lane == 0) out[0] = -s * (1.0f / 12000.0f);
    }
}

extern "C" void kernel_launch(void* const* d_in, const int* in_sizes, int n_in,
                              void* d_out, int out_size, void* d_ws, size_t ws_size,
                              hipStream_t stream)
{
    const float* y_true = (const float*)d_in[0];
    const float* y_pred = (const float*)d_in[1];
    float*    out     = (float*)d_out;
    float*    partial = (float*)d_ws;                         // 2000 floats
    unsigned* cnt     = (unsigned*)((char*)d_ws + 8192);      // 4-byte counter

    hipMemsetAsync(cnt, 0, sizeof(unsigned), stream);
    cr_patch_kernel<<<2 * NPATCH, 64, 0, stream>>>(y_true, y_pred, partial, cnt, out);
}